// Round 11
// baseline (1969.609 us; speedup 1.0000x reference)
//
#include <hip/hip_runtime.h>
#include <hip/hip_bf16.h>
#include <math.h>

using u16 = unsigned short;
using u32 = unsigned int;

typedef short s16x8 __attribute__((ext_vector_type(8)));
typedef float f32x4 __attribute__((ext_vector_type(4)));

__device__ __forceinline__ float bf2f(u16 u) {
  union { u32 i; float f; } c; c.i = ((u32)u) << 16; return c.f;
}
__device__ __forceinline__ u16 f2bf(float f) {
  union { float f; u32 i; } c; c.f = f;
  u32 r = c.i + 0x7fffu + ((c.i >> 16) & 1u);   // RNE; inputs are finite
  return (u16)(r >> 16);
}

__device__ __forceinline__ void gload_lds16(const u16* g, u16* l) {
  // async global->LDS, 16B/lane; LDS dest is wave-uniform base (lane*16 implicit)
  __builtin_amdgcn_global_load_lds(
      (const __attribute__((address_space(1))) void*)g,
      (__attribute__((address_space(3))) void*)l, 16, 0, 0);
}

// ------------- weight cast + transpose: W (K x N) f32 -> Wt (N x K) bf16, tiled -------------
__global__ __launch_bounds__(256) void castT_kernel(const float* __restrict__ W,
                                                    u16* __restrict__ Wt, int K, int N) {
  __shared__ float tile[32][33];
  int bn = blockIdx.x * 32, bk = blockIdx.y * 32;
  int tx = threadIdx.x & 31, ty = threadIdx.x >> 5;   // ty 0..7
#pragma unroll
  for (int i = 0; i < 4; i++)
    tile[ty + i * 8][tx] = W[(size_t)(bk + ty + i * 8) * N + bn + tx];   // coalesced in n
  __syncthreads();
#pragma unroll
  for (int i = 0; i < 4; i++)
    Wt[(size_t)(bn + ty + i * 8) * K + bk + tx] = f2bf(tile[tx][ty + i * 8]);  // coalesced in k
}

// ---------------- LayerNorm (C=512), one wave per token ----------------
template<int WINDOWED>
__global__ __launch_bounds__(256) void ln_kernel(const float* __restrict__ x,
                                                 const float* __restrict__ g,
                                                 const float* __restrict__ be,
                                                 u16* __restrict__ out) {
  int wid = threadIdx.x >> 6, lane = threadIdx.x & 63;
  int token = blockIdx.x * 4 + wid;           // 50176 tokens total
  const float4* xr = (const float4*)(x + (size_t)token * 512);
  float4 a = xr[lane * 2], b = xr[lane * 2 + 1];
  float s  = a.x + a.y + a.z + a.w + b.x + b.y + b.z + b.w;
  float sq = a.x*a.x + a.y*a.y + a.z*a.z + a.w*a.w + b.x*b.x + b.y*b.y + b.z*b.z + b.w*b.w;
#pragma unroll
  for (int off = 1; off < 64; off <<= 1) { s += __shfl_xor(s, off); sq += __shfl_xor(sq, off); }
  float mean = s * (1.f / 512.f);
  float var  = sq * (1.f / 512.f) - mean * mean;
  float rstd = rsqrtf(var + 1e-5f);
  size_t drow;
  if (WINDOWED) {
    int b_ = token / 3136, l = token - b_ * 3136;
    int Y = l / 56, X = l - Y * 56;
    int y = Y + 53; if (y >= 56) y -= 56;     // roll by -3
    int xx = X + 53; if (xx >= 56) xx -= 56;
    int widx = b_ * 64 + (y / 7) * 8 + (xx / 7);
    int p = (y % 7) * 7 + (xx % 7);
    drow = ((size_t)widx * 49 + p) * 512;
  } else {
    drow = (size_t)token * 512;
  }
  int c = lane * 8;
  float4 g0 = ((const float4*)(g + c))[0], g1v = ((const float4*)(g + c))[1];
  float4 b0 = ((const float4*)(be + c))[0], b1v = ((const float4*)(be + c))[1];
  float vals[8] = {a.x, a.y, a.z, a.w, b.x, b.y, b.z, b.w};
  float gv[8] = {g0.x, g0.y, g0.z, g0.w, g1v.x, g1v.y, g1v.z, g1v.w};
  float bv[8] = {b0.x, b0.y, b0.z, b0.w, b1v.x, b1v.y, b1v.z, b1v.w};
  uint4 pk; u32* pu = (u32*)&pk;
#pragma unroll
  for (int t = 0; t < 4; t++) {
    u16 lo = f2bf((vals[2*t]   - mean) * rstd * gv[2*t]   + bv[2*t]);
    u16 hi = f2bf((vals[2*t+1] - mean) * rstd * gv[2*t+1] + bv[2*t+1]);
    pu[t] = (u32)lo | ((u32)hi << 16);
  }
  *(uint4*)(out + drow + c) = pk;
}

// ---------------- GEMM 128x128, BK=32: C = A(MxK) @ Bt(NxK)^T, bf16 in / fp32 acc ---------
// A: 3-slot gload_lds ring (24 KiB), distance-2, counted vmcnt — never drained in-loop.
// B: weight matrix (<=2MB, L2-resident) -> fragments loaded DIRECTLY global->VGPR with
// REGISTER double-buffering (bA/bB, 2x-unrolled loop, no copies). Fixes r4's failure:
// B(t+1) is issued BEFORE A-stage(t+2), so the wait for B(t) (own asm vmcnt(8) == the
// compiler's exact count) leaves {A(t+1),B(t+1),A(t+2)} = 8 ops in flight — B has a full
// iteration of cover (L2 ~200cyc), A has two. ds_read halves (4/wave/step, A only) and
// barriers halve (ONE raw s_barrier per K-step; 3 slots make this race-free: stage targets
// slot (s+2)%3 which holds tile t-1, whose ds_reads completed before each wave's body-t
// barrier arrival via the compiler's lgkmcnt before MFMA).
// Ledger (uniform incl. prologue A0,B0,A1): vmcnt(6) forces A(t); vmcnt(8) forces B(t).
// MODE 1/3 epilogues route through LDS ([32][132] f32 overlay, 4 passes): 512B-contiguous
// global fp32 runs. MODE 0: +b_qkv scatter to qb/kb/vb blocked (w,h,p,d).
// MODE 2: +b1, tanh-GELU, bf16 w-order.
template<int MODE>
__global__ __launch_bounds__(256, 4) void gemm_bt(
    const u16* __restrict__ A, const u16* __restrict__ Bt,
    const float* __restrict__ bias,
    float* __restrict__ fout, u16* __restrict__ bout,
    const float* __restrict__ resid,
    int N, int K,
    u16* __restrict__ q_out, u16* __restrict__ k_out, u16* __restrict__ v_out) {
  __shared__ __align__(16) u16 Smem[12288];       // 24 KiB: 3 A-slots (8KB) + epilogue overlay
  u16 (*As)[4096] = (u16 (*)[4096])Smem;
  int tid = threadIdx.x;
  int wid = tid >> 6, lane = tid & 63;

  // XCD-aware tile remap: contiguous runs of M-tiles (all their N-tiles) per XCD.
  int nbx = gridDim.x;
  int lin = blockIdx.y * nbx + blockIdx.x;
  int tot = nbx * gridDim.y;
  int bx, by;
  if ((tot & 7) == 0) {
    int per = tot >> 3;
    int nl = (lin & 7) * per + (lin >> 3);
    by = nl / nbx; bx = nl - by * nbx;
  } else { bx = blockIdx.x; by = blockIdx.y; }
  int tileM = by * 128;
  int tileN = bx * 128;
  int wm = (wid >> 1) * 64, wn = (wid & 1) * 64;

  f32x4 acc[4][4];
#pragma unroll
  for (int i = 0; i < 4; i++)
#pragma unroll
    for (int j = 0; j < 4; j++) acc[i][j] = (f32x4){0.f, 0.f, 0.f, 0.f};

  // A staging: per K-tile (128x32 = 8 KiB) each wave issues 2 gloads (chunks of 16 rows).
  // lane -> row rl = lane>>2, granule pos gp = lane&3; LDS pos gp holds source granule
  // gp ^ ((rl>>1)&3) -> conflict-free ds_read_b128 swizzle (PMC-verified 0 conflicts).
  int rl = lane >> 2;
  int gsrc = (lane & 3) ^ ((rl >> 1) & 3);
  int c0 = wid * 2, c1 = wid * 2 + 1;
  const u16* Ab0 = A + (size_t)(tileM + c0 * 16 + rl) * K + gsrc * 8;
  const u16* Ab1 = A + (size_t)(tileM + c1 * 16 + rl) * K + gsrc * 8;

#define STAGE_A(koff, s) do {                          \
    gload_lds16(Ab0 + (koff), &As[(s)][c0 * 512]);     \
    gload_lds16(Ab1 + (koff), &As[(s)][c1 * 512]);     \
  } while (0)

  // read geometry: frag row lrow = lane&15, k-granule lq = lane>>4.
  int lrow = lane & 15, lq = lane >> 4;
  int pos8 = (lq ^ ((lrow >> 1) & 3)) * 8;
  int aoff = (wm + lrow) * 32 + pos8;

  // B fragment pointers (L2-resident weights; no swizzle needed)
  const u16* Bb[4];
#pragma unroll
  for (int nf = 0; nf < 4; nf++)
    Bb[nf] = Bt + (size_t)(tileN + wn + nf * 16 + lrow) * K + lq * 8;

  int NT = K >> 5;   // K-tiles of 32 (K=512 -> 16, K=2048 -> 64; always even)

  s16x8 bA[4], bB[4];
  // prologue (issue order A0, B0, A1 -> uniform ledger)
  STAGE_A(0, 0);
#pragma unroll
  for (int nf = 0; nf < 4; nf++) bA[nf] = *(const s16x8*)(Bb[nf]);
  STAGE_A(32, 1);

#define GBODY(t, s, bThis, bOther) do {                                                    \
    asm volatile("s_waitcnt vmcnt(6)" ::: "memory");   /* own A(t) landed */               \
    __builtin_amdgcn_s_barrier();                      /* all A(t) landed; t-1 reads done */\
    const u16* sa = &As[(s)][aoff];                                                        \
    s16x8 af[4];                                                                           \
    _Pragma("unroll") for (int mf = 0; mf < 4; mf++) af[mf] = *(const s16x8*)(sa + mf * 512); \
    int kb_ = ((t) + 1 < NT ? (t) + 1 : NT - 1) * 32;                                      \
    _Pragma("unroll") for (int nf = 0; nf < 4; nf++)                                       \
      bOther[nf] = *(const s16x8*)(Bb[nf] + kb_);     /* B(t+1) -> regs, BEFORE A-stage */ \
    int ka_ = ((t) + 2 < NT ? (t) + 2 : NT - 1) * 32;                                      \
    STAGE_A(ka_, ((s) + 2 >= 3 ? (s) - 1 : (s) + 2)); /* A(t+2) -> slot holding t-1 */     \
    asm volatile("s_waitcnt vmcnt(8)" ::: "memory");   /* B(t) landed; 8 newer in flight */ \
    __builtin_amdgcn_s_setprio(1);                                                         \
    _Pragma("unroll") for (int mf = 0; mf < 4; mf++)                                       \
      _Pragma("unroll") for (int nf = 0; nf < 4; nf++)                                     \
        acc[mf][nf] = __builtin_amdgcn_mfma_f32_16x16x32_bf16(af[mf], bThis[nf], acc[mf][nf], 0, 0, 0); \
    __builtin_amdgcn_s_setprio(0);                                                         \
  } while (0)

  int slot = 0;
  for (int t = 0; t < NT; t += 2) {
    GBODY(t, slot, bA, bB);
    slot = (slot == 2) ? 0 : slot + 1;
    GBODY(t + 1, slot, bB, bA);
    slot = (slot == 2) ? 0 : slot + 1;
  }
#undef GBODY
#undef STAGE_A

  int lcol = lane & 15;
  int lr4 = (lane >> 4) * 4;

  if (MODE == 1 || MODE == 3) {
    // ---- LDS-transposed fp32 epilogue: 512B-contiguous global segments ----
    asm volatile("s_waitcnt vmcnt(0)" ::: "memory");   // drain tail clamped stage (LDS writes!)
    __syncthreads();
    float* Ef = (float*)Smem;                 // [32][132] f32 = 16896B <= 24576B
    int lrbase = (wid >> 1) * 16 + lr4;       // local row 0..31 per mt pass
    int lrow_ep = tid >> 3, q = tid & 7;      // commit: row 0..31, 64B slice q of 512B run
#pragma unroll
    for (int mt = 0; mt < 4; mt++) {
#pragma unroll
      for (int nt = 0; nt < 4; nt++) {
        int col = wn + nt * 16 + lcol;
        float bv = bias[tileN + col];
#pragma unroll
        for (int r = 0; r < 4; r++)
          Ef[(lrbase + r) * 132 + col] = acc[mt][nt][r] + bv;
      }
      __syncthreads();
      int grow = tileM + (lrow_ep >> 4) * 64 + mt * 16 + (lrow_ep & 15);
      int widx = grow / 49, p = grow - widx * 49;
      int b_ = widx >> 6, wi = (widx >> 3) & 7, wj = widx & 7;
      int i = p / 7, j2 = p - i * 7;
      int Y = wi * 7 + i + 3; if (Y >= 56) Y -= 56;   // roll back by +3
      int X = wj * 7 + j2 + 3; if (X >= 56) X -= 56;
      size_t srow = ((size_t)b_ * 3136 + Y * 56 + X) * 512;
      size_t wrow = (size_t)grow * 512;
      const float* rsrc = resid + (MODE == 1 ? srow : wrow) + tileN + q * 16;
      float* wdst = fout + (MODE == 1 ? wrow : srow) + tileN + q * 16;
      const float* ls = &Ef[lrow_ep * 132 + q * 16];
#pragma unroll
      for (int j = 0; j < 4; j++) {
        float4 v = *(const float4*)(ls + j * 4);
        float4 rd = *(const float4*)(rsrc + j * 4);
        v.x += rd.x; v.y += rd.y; v.z += rd.z; v.w += rd.w;
        *(float4*)(wdst + j * 4) = v;
      }
      __syncthreads();
    }
  } else {
#pragma unroll
    for (int mt = 0; mt < 4; mt++) {
#pragma unroll
      for (int r = 0; r < 4; r++) {
        int row = tileM + wm + mt * 16 + lr4 + r;
        if (MODE == 0) {
          // scatter to blocked (w,h,p,d): 16 consecutive lanes -> consecutive d (32B segments)
          int widx = row / 49, p = row - widx * 49;
#pragma unroll
          for (int nt = 0; nt < 4; nt++) {
            int col = tileN + wn + nt * 16 + lcol;
            float val = acc[mt][nt][r] + bias[col];
            int sel = col >> 9, h = (col >> 5) & 15, d = col & 31;
            u16* dst = (sel == 0) ? q_out : (sel == 1 ? k_out : v_out);
            dst[(((size_t)widx * 16 + h) * 49 + p) * 32 + d] = f2bf(val);
          }
        } else {
          size_t rb = (size_t)row * N;
#pragma unroll
          for (int nt = 0; nt < 4; nt++) {
            int col = tileN + wn + nt * 16 + lcol;
            float tv = acc[mt][nt][r] + bias[col];
            // tanh-GELU: t*sigmoid(1.59577(t+.044715t^3))
            float u = tv + 0.044715f * tv * tv * tv;
            float gel = tv * __builtin_amdgcn_rcpf(1.f + __expf(-1.5957691216057308f * u));
            bout[rb + col] = f2bf(gel);
          }
        }
      }
    }
  }
}

// ---------------- window attention via MFMA: one wave per (window, head); N=49, dh=32 -------
// qb/kb/vb blocked (w,h,p,d) bf16: this block's q/k/v are 3 contiguous 3.1KB streams.
// S^T = mfma(K,Q): C-layout col=q=lane&15, row=m -> softmax over m = 16 in-lane vals +
// shfl_xor(16,32). P normalized in-reg, packed bf16, bounced through LDS Pl[q][mp]
// (stride 36 u32) to convert C-layout -> A-frag. PV = mfma(P,V). Padded rows/cols masked
// to -1e30 pre-softmax (invalid-q columns land only in unwritten out rows).
__global__ __launch_bounds__(64) void attn_kernel(
    const u16* __restrict__ qb, const u16* __restrict__ kb, const u16* __restrict__ vb,
    const float* __restrict__ btab, u16* __restrict__ out) {
  __shared__ float bcol[176];
  __shared__ u32 Pl[64 * 36];
  int blk = blockIdx.x;
  int h = blk & 15, w = blk >> 4;
  int lane = threadIdx.x;
  int c = lane & 15, g = lane >> 4;
  int hc = h * 32;
  size_t base = (size_t)blk * 1568;      // 49*32 elements per (w,h)

  for (int i = lane; i < 169; i += 64) bcol[i] = btab[i * 16 + h];

  const s16x8 z8 = (s16x8){0, 0, 0, 0, 0, 0, 0, 0};
  // Q as B-frags (col=q=lane&15, k=d=8g+j), K as A-frags (row=m=lane&15, k=d):
  // 16B/lane, 16 consecutive rows -> 1KB contiguous per frag load (fully coalesced)
  s16x8 qf[4], kf[4];
#pragma unroll
  for (int t = 0; t < 4; t++) {
    int qq = 16 * t + c;
    if (qq < 49) {
      qf[t] = *(const s16x8*)(qb + base + qq * 32 + g * 8);
      kf[t] = *(const s16x8*)(kb + base + qq * 32 + g * 8);
    } else { qf[t] = z8; kf[t] = z8; }
  }
  // V as B-frags for PV (col=d=16dt+c, k=m=32ks+8g+j): scalar bf16, 32B segments within
  // the contiguous 3.1KB v-block (L2-hot after first touch)
  s16x8 vf[2][2];
#pragma unroll
  for (int ks = 0; ks < 2; ks++)
#pragma unroll
    for (int dt = 0; dt < 2; dt++) {
      s16x8 v = z8;
#pragma unroll
      for (int j = 0; j < 8; j++) {
        int m = 32 * ks + 8 * g + j;
        if (m < 49) v[j] = (short)vb[base + m * 32 + 16 * dt + c];
      }
      vf[ks][dt] = v;
    }

  // S^T[m][q] tiles
  f32x4 s[4][4];
#pragma unroll
  for (int mt = 0; mt < 4; mt++)
#pragma unroll
    for (int nt = 0; nt < 4; nt++)
      s[mt][nt] = __builtin_amdgcn_mfma_f32_16x16x32_bf16(
          kf[mt], qf[nt], (f32x4){0.f, 0.f, 0.f, 0.f}, 0, 0, 0);

  // per-lane bias index tables: bidx = (qi*13+qj+84) - (mi*13+mj)
  int qb_[4]; bool qv[4];
#pragma unroll
  for (int nt = 0; nt < 4; nt++) {
    int qq = 16 * nt + c;
    qv[nt] = qq < 49;
    int qi = qq / 7, qj = qq - qi * 7;
    qb_[nt] = qi * 13 + qj + 84;
  }
  int mb_[4][4]; bool mv[4][4];
#pragma unroll
  for (int mt = 0; mt < 4; mt++)
#pragma unroll
    for (int r = 0; r < 4; r++) {
      int m = 16 * mt + 4 * g + r;
      mv[mt][r] = m < 49;
      int mi = m / 7, mj = m - mi * 7;
      mb_[mt][r] = mi * 13 + mj;
    }

  const float scale = 0.17677669529663689f;
#pragma unroll
  for (int nt = 0; nt < 4; nt++) {
    float mxl = -1e30f;
#pragma unroll
    for (int mt = 0; mt < 4; mt++)
#pragma unroll
      for (int r = 0; r < 4; r++) {
        int bi = qb_[nt] - mb_[mt][r];
        bi = bi < 0 ? 0 : (bi > 168 ? 168 : bi);          // clamp: no OOB LDS even when masked
        float v = (qv[nt] && mv[mt][r]) ? fmaf(s[mt][nt][r], scale, bcol[bi]) : -1e30f;
        s[mt][nt][r] = v;
        mxl = fmaxf(mxl, v);
      }
    mxl = fmaxf(mxl, __shfl_xor(mxl, 16));
    mxl = fmaxf(mxl, __shfl_xor(mxl, 32));
    float sml = 0.f;
#pragma unroll
    for (int mt = 0; mt < 4; mt++)
#pragma unroll
      for (int r = 0; r < 4; r++) {
        float ev = __expf(s[mt][nt][r] - mxl);
        s[mt][nt][r] = ev;
        sml += ev;
      }
    sml += __shfl_xor(sml, 16);
    sml += __shfl_xor(sml, 32);
    float inv = 1.f / sml;
#pragma unroll
    for (int mt = 0; mt < 4; mt++)
#pragma unroll
      for (int r = 0; r < 4; r++)
        s[mt][nt][r] *= inv;                              // fold softmax denom into P
  }

  // pack P to bf16 pairs -> LDS: Pl[q*36 + mp], u32 mp holds (m=2mp lo, m=2mp+1 hi)
#pragma unroll
  for (int nt = 0; nt < 4; nt++) {
    int qq = 16 * nt + c;
#pragma unroll
    for (int mt = 0; mt < 4; mt++) {
      u32 p0 = (u32)f2bf(s[mt][nt][0]) | ((u32)f2bf(s[mt][nt][1]) << 16);
      u32 p1 = (u32)f2bf(s[mt][nt][2]) | ((u32)f2bf(s[mt][nt][3]) << 16);
      int mp = 8 * mt + 2 * g;
      Pl[qq * 36 + mp] = p0;
      Pl[qq * 36 + mp + 1] = p1;
    }
  }
  asm volatile("" ::: "memory");   // keep ds_writes before ds_reads (single wave: DS in-order)

  f32x4 o[4][2];
#pragma unroll
  for (int qt = 0; qt < 4; qt++)
#pragma unroll
    for (int dt = 0; dt < 2; dt++) o[qt][dt] = (f32x4){0.f, 0.f, 0.f, 0.f};
#pragma unroll
  for (int qt = 0; qt < 4; qt++) {
#pragma unroll
    for (int ks = 0; ks < 2; ks++) {
      // A-frag: row=q=lane&15, k=m=32ks+8g+j -> 4 consecutive u32 at mp=16ks+4g
      s16x8 pf = *(const s16x8*)&Pl[(16 * qt + c) * 36 + 16 * ks + 4 * g];
#pragma unroll
      for (int dt = 0; dt < 2; dt++)
        o[qt][dt] = __builtin_amdgcn_mfma_f32_16x16x32_bf16(pf, vf[ks][dt], o[qt][dt], 0, 0, 0);
    }
  }
  // out C-layout: col=d=16dt+c, row=q=16qt+4g+r; 32B contiguous segments per (g,r)
#pragma unroll
  for (int qt = 0; qt < 4; qt++)
#pragma unroll
    for (int dt = 0; dt < 2; dt++)
#pragma unroll
      for (int r = 0; r < 4; r++) {
        int qq = 16 * qt + 4 * g + r;
        if (qq < 49)
          out[((size_t)w * 49 + qq) * 512 + hc + 16 * dt + c] = f2bf(o[qt][dt][r]);
      }
}

extern "C" void kernel_launch(void* const* d_in, const int* in_sizes, int n_in,
                              void* d_out, int out_size, void* d_ws, size_t ws_size,
                              hipStream_t stream) {
  (void)in_sizes; (void)n_in; (void)out_size; (void)ws_size;
  const float* x        = (const float*)d_in[0];
  const float* w_qkv    = (const float*)d_in[3];
  const float* b_qkv    = (const float*)d_in[4];
  const float* w_proj   = (const float*)d_in[5];
  const float* b_proj   = (const float*)d_in[6];
  const float* bias_tab = (const float*)d_in[7];
  const float* g1       = (const float*)d_in[8];
  const float* be1      = (const float*)d_in[9];
  const float* g2       = (const float*)d_in[10];
  const float* be2      = (const float*)d_in[11];
  const float* w1       = (const float*)d_in[12];
  const float* b1       = (const float*)d_in[13];
  const float* w2       = (const float*)d_in[14];
  const float* b2       = (const float*)d_in[15];

  char* ws = (char*)d_ws;
  // workspace layout (liveness-based reuse):
  u16* wqkvT  = (u16*)(ws + 0);            // 1536x512 bf16
  u16* wprojT = (u16*)(ws + 1572864);      //  512x512
  u16* w1T    = (u16*)(ws + 2097152);      // 2048x512
  u16* w2T    = (u16*)(ws + 4194304);      //  512x2048
  u16* xw     = (u16*)(ws + 6291456);      // R1: 50176x512 bf16 (windowed LN1 out)
  u16* attn_o = xw;                        // R1 reuse
  u16* h2     = xw;                        // R1 reuse
  char* R2    = ws + 57671680;
  u16* qb = (u16*)R2;                      // each 1024*16*49*32 bf16 = 51,380,224 B
  u16* kb = (u16*)(R2 + 51380224);
  u16* vb = (u16*)(R2 + 102760448);
  float* x_res = (float*)R2;               // R2 reuse (qkv dead after attention); w-order rows
  u16* hidden  = (u16*)(ws + 160432128);   // 50176x2048 bf16 (after x_res; vb dead by then)
  float* outp  = (float*)d_out;

  castT_kernel<<<dim3(1536 / 32, 512 / 32), 256, 0, stream>>>(w_qkv, wqkvT, 512, 1536);
  castT_kernel<<<dim3(512 / 32, 512 / 32), 256, 0, stream>>>(w_proj, wprojT, 512, 512);
  castT_kernel<<<dim3(2048 / 32, 512 / 32), 256, 0, stream>>>(w1, w1T, 512, 2048);
  castT_kernel<<<dim3(512 / 32, 2048 / 32), 256, 0, stream>>>(w2, w2T, 2048, 512);

  ln_kernel<1><<<12544, 256, 0, stream>>>(x, g1, be1, xw);
  gemm_bt<0><<<dim3(12, 392), 256, 0, stream>>>(xw, wqkvT, b_qkv, nullptr, nullptr, nullptr,
                                                1536, 512, qb, kb, vb);
  attn_kernel<<<16384, 64, 0, stream>>>(qb, kb, vb, bias_tab, attn_o);
  gemm_bt<1><<<dim3(4, 392), 256, 0, stream>>>(attn_o, wprojT, b_proj, x_res, nullptr, x,
                                               512, 512, nullptr, nullptr, nullptr);
  ln_kernel<0><<<12544, 256, 0, stream>>>(x_res, g2, be2, h2);
  gemm_bt<2><<<dim3(16, 392), 256, 0, stream>>>(h2, w1T, b1, nullptr, hidden, nullptr,
                                                2048, 512, nullptr, nullptr, nullptr);
  gemm_bt<3><<<dim3(4, 392), 256, 0, stream>>>(hidden, w2T, b2, outp, nullptr, x_res,
                                               512, 2048, nullptr, nullptr, nullptr);
}

// Round 12
// 809.711 us; speedup vs baseline: 2.4325x; 2.4325x over previous
//
#include <hip/hip_runtime.h>
#include <hip/hip_bf16.h>
#include <math.h>

using u16 = unsigned short;
using u32 = unsigned int;

typedef short s16x8 __attribute__((ext_vector_type(8)));
typedef float f32x4 __attribute__((ext_vector_type(4)));

__device__ __forceinline__ float bf2f(u16 u) {
  union { u32 i; float f; } c; c.i = ((u32)u) << 16; return c.f;
}
__device__ __forceinline__ u16 f2bf(float f) {
  union { float f; u32 i; } c; c.f = f;
  u32 r = c.i + 0x7fffu + ((c.i >> 16) & 1u);   // RNE; inputs are finite
  return (u16)(r >> 16);
}

__device__ __forceinline__ void gload_lds16(const u16* g, u16* l) {
  // async global->LDS, 16B/lane; LDS dest is wave-uniform base (lane*16 implicit)
  __builtin_amdgcn_global_load_lds(
      (const __attribute__((address_space(1))) void*)g,
      (__attribute__((address_space(3))) void*)l, 16, 0, 0);
}

// ------------- weight cast + transpose: W (K x N) f32 -> Wt (N x K) bf16, tiled -------------
__global__ __launch_bounds__(256) void castT_kernel(const float* __restrict__ W,
                                                    u16* __restrict__ Wt, int K, int N) {
  __shared__ float tile[32][33];
  int bn = blockIdx.x * 32, bk = blockIdx.y * 32;
  int tx = threadIdx.x & 31, ty = threadIdx.x >> 5;   // ty 0..7
#pragma unroll
  for (int i = 0; i < 4; i++)
    tile[ty + i * 8][tx] = W[(size_t)(bk + ty + i * 8) * N + bn + tx];   // coalesced in n
  __syncthreads();
#pragma unroll
  for (int i = 0; i < 4; i++)
    Wt[(size_t)(bn + ty + i * 8) * K + bk + tx] = f2bf(tile[tx][ty + i * 8]);  // coalesced in k
}

// ---------------- LayerNorm (C=512), one wave per token ----------------
template<int WINDOWED>
__global__ __launch_bounds__(256) void ln_kernel(const float* __restrict__ x,
                                                 const float* __restrict__ g,
                                                 const float* __restrict__ be,
                                                 u16* __restrict__ out) {
  int wid = threadIdx.x >> 6, lane = threadIdx.x & 63;
  int token = blockIdx.x * 4 + wid;           // 50176 tokens total
  const float4* xr = (const float4*)(x + (size_t)token * 512);
  float4 a = xr[lane * 2], b = xr[lane * 2 + 1];
  float s  = a.x + a.y + a.z + a.w + b.x + b.y + b.z + b.w;
  float sq = a.x*a.x + a.y*a.y + a.z*a.z + a.w*a.w + b.x*b.x + b.y*b.y + b.z*b.z + b.w*b.w;
#pragma unroll
  for (int off = 1; off < 64; off <<= 1) { s += __shfl_xor(s, off); sq += __shfl_xor(sq, off); }
  float mean = s * (1.f / 512.f);
  float var  = sq * (1.f / 512.f) - mean * mean;
  float rstd = rsqrtf(var + 1e-5f);
  size_t drow;
  if (WINDOWED) {
    int b_ = token / 3136, l = token - b_ * 3136;
    int Y = l / 56, X = l - Y * 56;
    int y = Y + 53; if (y >= 56) y -= 56;     // roll by -3
    int xx = X + 53; if (xx >= 56) xx -= 56;
    int widx = b_ * 64 + (y / 7) * 8 + (xx / 7);
    int p = (y % 7) * 7 + (xx % 7);
    drow = ((size_t)widx * 49 + p) * 512;
  } else {
    drow = (size_t)token * 512;
  }
  int c = lane * 8;
  float4 g0 = ((const float4*)(g + c))[0], g1v = ((const float4*)(g + c))[1];
  float4 b0 = ((const float4*)(be + c))[0], b1v = ((const float4*)(be + c))[1];
  float vals[8] = {a.x, a.y, a.z, a.w, b.x, b.y, b.z, b.w};
  float gv[8] = {g0.x, g0.y, g0.z, g0.w, g1v.x, g1v.y, g1v.z, g1v.w};
  float bv[8] = {b0.x, b0.y, b0.z, b0.w, b1v.x, b1v.y, b1v.z, b1v.w};
  uint4 pk; u32* pu = (u32*)&pk;
#pragma unroll
  for (int t = 0; t < 4; t++) {
    u16 lo = f2bf((vals[2*t]   - mean) * rstd * gv[2*t]   + bv[2*t]);
    u16 hi = f2bf((vals[2*t+1] - mean) * rstd * gv[2*t+1] + bv[2*t+1]);
    pu[t] = (u32)lo | ((u32)hi << 16);
  }
  *(uint4*)(out + drow + c) = pk;
}

// ---------------- GEMM 128x128, BK=32, 2-slot LDS ring: C = A(MxK) @ Bt(NxK)^T ----------------
// 256 threads = 4 waves (2Mx2N), wave tile 64x64. LDS = 32 KiB shared carve (ring + epilogue).
// 5 blocks/CU co-resident (LDS-limited). launch_bounds(256,4): VGPR cap 128 (r6/r11 lesson:
// tighter floors or extra live register state -> acc spills to scratch, 2.1-2.4x slower;
// B stays in LDS — both B-direct-to-VGPR designs failed: r4 in-order-vmcnt serialization,
// r11 register-pressure spill).
// Distance-1 counted ring, never drains vmcnt in-loop; ledger: 4 loads/iter, wait at 4,
// tail clamped. Granule-xor swizzle -> conflict-free ds_read_b128 (PMC=0).
// MODE 1/3 epilogues route through LDS ([32][132] f32, 4 passes): global fp32 read+write
// in 512B-contiguous runs. MODE 2 epilogue routes through LDS ([32][136] u16): bf16 writes
// in 256B-contiguous runs (was scalar u16 / 32B segments on 205MB).
// MODE 0: +b_qkv, scatter to qb/kb/vb blocked (w,h,p,d) bf16 -> attn reads contiguous
// MODE 1: +b_proj, write x_res fp32 in w-order; resid = x gathered at perm rows
// MODE 2: +b1, tanh-GELU, write bf16 (w-order)
// MODE 3: +b2 + x_res (w-order), write fp32 final output at perm rows
template<int MODE>
__global__ __launch_bounds__(256, 4) void gemm_bt(
    const u16* __restrict__ A, const u16* __restrict__ Bt,
    const float* __restrict__ bias,
    float* __restrict__ fout, u16* __restrict__ bout,
    const float* __restrict__ resid,
    int N, int K,
    u16* __restrict__ q_out, u16* __restrict__ k_out, u16* __restrict__ v_out) {
  __shared__ __align__(16) u16 Smem[16384];   // 32 KiB: ring slots + epilogue buffer
  u16 (*As)[4096] = (u16 (*)[4096])Smem;          // 2 slots x 128 rows x 32
  u16 (*Bs)[4096] = (u16 (*)[4096])(Smem + 8192);
  int tid = threadIdx.x;
  int wid = tid >> 6, lane = tid & 63;

  // XCD-aware tile remap: contiguous runs of M-tiles (all their N-tiles) per XCD.
  int nbx = gridDim.x;
  int lin = blockIdx.y * nbx + blockIdx.x;
  int tot = nbx * gridDim.y;
  int bx, by;
  if ((tot & 7) == 0) {
    int per = tot >> 3;
    int nl = (lin & 7) * per + (lin >> 3);
    by = nl / nbx; bx = nl - by * nbx;
  } else { bx = blockIdx.x; by = blockIdx.y; }
  int tileM = by * 128;
  int tileN = bx * 128;
  int wm = (wid >> 1) * 64, wn = (wid & 1) * 64;

  f32x4 acc[4][4];
#pragma unroll
  for (int i = 0; i < 4; i++)
#pragma unroll
    for (int j = 0; j < 4; j++) acc[i][j] = (f32x4){0.f, 0.f, 0.f, 0.f};

  // staging: per K-tile (128x32 = 8 KiB per matrix) each wave issues 2 A + 2 B gloads (1 KiB).
  // chunk c = 16 rows x 32 cols; lane -> row rl = lane>>2, granule pos gp = lane&3.
  // LDS pos gp holds source granule gp ^ ((rl>>1)&3)  -> conflict-free read swizzle.
  int rl = lane >> 2;
  int gsrc = (lane & 3) ^ ((rl >> 1) & 3);
  int c0 = wid * 2, c1 = wid * 2 + 1;
  const u16* Ab0 = A  + (size_t)(tileM + c0 * 16 + rl) * K + gsrc * 8;
  const u16* Ab1 = A  + (size_t)(tileM + c1 * 16 + rl) * K + gsrc * 8;
  const u16* Bb0 = Bt + (size_t)(tileN + c0 * 16 + rl) * K + gsrc * 8;
  const u16* Bb1 = Bt + (size_t)(tileN + c1 * 16 + rl) * K + gsrc * 8;

#define STAGE_RING(koff, slot) do {                      \
    gload_lds16(Ab0 + (koff), &As[(slot)][c0 * 512]);    \
    gload_lds16(Ab1 + (koff), &As[(slot)][c1 * 512]);    \
    gload_lds16(Bb0 + (koff), &Bs[(slot)][c0 * 512]);    \
    gload_lds16(Bb1 + (koff), &Bs[(slot)][c1 * 512]);    \
  } while (0)

  // read geometry: frag row lrow = lane&15, k-granule lq = lane>>4,
  // LDS pos = lq ^ ((lrow>>1)&3)  (conflict-free, PMC-verified).
  int lrow = lane & 15, lq = lane >> 4;
  int pos8 = (lq ^ ((lrow >> 1) & 3)) * 8;
  int aoff = (wm + lrow) * 32 + pos8;
  int boff = (wn + lrow) * 32 + pos8;

  int NT = K >> 5;   // K-tiles of 32 (K=512 -> 16, K=2048 -> 64)

  // prologue: stage tile 0 only (4 loads/wave in flight)
  STAGE_RING(0, 0);

  for (int t = 0; t < NT; t++) {
    int slot = t & 1;
    __builtin_amdgcn_s_barrier();            // all reads of tile t-1 consumed block-wide
    // stage tile t+1 into the other slot (tile t-1's data is dead); clamp at tail so
    // every iteration issues exactly 4 loads (uniform vmcnt ledger).
    int src = (t + 1 < NT) ? t + 1 : NT - 1;
    STAGE_RING(src * 32, slot ^ 1);
    asm volatile("s_waitcnt vmcnt(4)" ::: "memory");   // own stage(t) landed; t+1 in flight
    __builtin_amdgcn_s_barrier();            // everyone's stage(t) landed
    asm volatile("" ::: "memory");
    const u16* sa = &As[slot][aoff];
    const u16* sb = &Bs[slot][boff];
    s16x8 af[4], bfr[4];
#pragma unroll
    for (int mf = 0; mf < 4; mf++) af[mf] = *(const s16x8*)(sa + mf * 512);
#pragma unroll
    for (int nf = 0; nf < 4; nf++) bfr[nf] = *(const s16x8*)(sb + nf * 512);
    __builtin_amdgcn_s_setprio(1);
#pragma unroll
    for (int mf = 0; mf < 4; mf++)
#pragma unroll
      for (int nf = 0; nf < 4; nf++)
        acc[mf][nf] = __builtin_amdgcn_mfma_f32_16x16x32_bf16(af[mf], bfr[nf], acc[mf][nf], 0, 0, 0);
    __builtin_amdgcn_s_setprio(0);
  }
#undef STAGE_RING

  int lcol = lane & 15;
  int lr4 = (lane >> 4) * 4;

  if (MODE == 1 || MODE == 3) {
    // ---- LDS-transposed fp32 epilogue: 512B-contiguous global segments ----
    asm volatile("s_waitcnt vmcnt(0)" ::: "memory");   // drain tail clamped stage (LDS writes!)
    __syncthreads();
    float* Ef = (float*)Smem;                 // [32][132] f32 (pad 132 -> 2-way banks, free)
    int lrbase = (wid >> 1) * 16 + lr4;       // local row 0..31 per mt pass
    int lrow_ep = tid >> 3, q = tid & 7;      // commit: row 0..31, 64B slice q of 512B run
#pragma unroll
    for (int mt = 0; mt < 4; mt++) {
#pragma unroll
      for (int nt = 0; nt < 4; nt++) {
        int col = wn + nt * 16 + lcol;
        float bv = bias[tileN + col];
#pragma unroll
        for (int r = 0; r < 4; r++)
          Ef[(lrbase + r) * 132 + col] = acc[mt][nt][r] + bv;
      }
      __syncthreads();
      int grow = tileM + (lrow_ep >> 4) * 64 + mt * 16 + (lrow_ep & 15);
      int widx = grow / 49, p = grow - widx * 49;
      int b_ = widx >> 6, wi = (widx >> 3) & 7, wj = widx & 7;
      int i = p / 7, j2 = p - i * 7;
      int Y = wi * 7 + i + 3; if (Y >= 56) Y -= 56;   // roll back by +3
      int X = wj * 7 + j2 + 3; if (X >= 56) X -= 56;
      size_t srow = ((size_t)b_ * 3136 + Y * 56 + X) * 512;
      size_t wrow = (size_t)grow * 512;
      const float* rsrc = resid + (MODE == 1 ? srow : wrow) + tileN + q * 16;
      float* wdst = fout + (MODE == 1 ? wrow : srow) + tileN + q * 16;
      const float* ls = &Ef[lrow_ep * 132 + q * 16];
#pragma unroll
      for (int j = 0; j < 4; j++) {
        float4 v = *(const float4*)(ls + j * 4);
        float4 rd = *(const float4*)(rsrc + j * 4);
        v.x += rd.x; v.y += rd.y; v.z += rd.z; v.w += rd.w;
        *(float4*)(wdst + j * 4) = v;
      }
      __syncthreads();
    }
  } else if (MODE == 2) {
    // ---- LDS-packed bf16 epilogue: 256B-contiguous runs (was scalar u16 / 32B) ----
    asm volatile("s_waitcnt vmcnt(0)" ::: "memory");   // drain tail clamped stage
    __syncthreads();
    u16* Eh = (u16*)Smem;                     // [32][136] u16 = 8704B <= 32KB
    int lrbase = (wid >> 1) * 16 + lr4;
    int lrow_ep = tid >> 3, q = tid & 7;      // commit: row 0..31, 32B slice q of 256B run
#pragma unroll
    for (int mt = 0; mt < 4; mt++) {
#pragma unroll
      for (int nt = 0; nt < 4; nt++) {
        int col = wn + nt * 16 + lcol;
        float bv = bias[tileN + col];
#pragma unroll
        for (int r = 0; r < 4; r++) {
          float tv = acc[mt][nt][r] + bv;
          // tanh-GELU: t*sigmoid(1.59577(t+.044715t^3))
          float u = tv + 0.044715f * tv * tv * tv;
          float gel = tv * __builtin_amdgcn_rcpf(1.f + __expf(-1.5957691216057308f * u));
          Eh[(lrbase + r) * 136 + col] = f2bf(gel);
        }
      }
      __syncthreads();
      int grow = tileM + (lrow_ep >> 4) * 64 + mt * 16 + (lrow_ep & 15);
      u16* wdst = bout + (size_t)grow * N + tileN + q * 16;
      const u16* ls = &Eh[lrow_ep * 136 + q * 16];
      *(uint4*)(wdst)     = *(const uint4*)(ls);
      *(uint4*)(wdst + 8) = *(const uint4*)(ls + 8);
      __syncthreads();
    }
  } else {
#pragma unroll
    for (int mt = 0; mt < 4; mt++) {
#pragma unroll
      for (int r = 0; r < 4; r++) {
        int row = tileM + wm + mt * 16 + lr4 + r;
        // MODE 0: scatter to blocked (w,h,p,d): 16 consecutive lanes -> consecutive d (32B)
        int widx = row / 49, p = row - widx * 49;
#pragma unroll
        for (int nt = 0; nt < 4; nt++) {
          int col = tileN + wn + nt * 16 + lcol;
          float val = acc[mt][nt][r] + bias[col];
          int sel = col >> 9, h = (col >> 5) & 15, d = col & 31;
          u16* dst = (sel == 0) ? q_out : (sel == 1 ? k_out : v_out);
          dst[(((size_t)widx * 16 + h) * 49 + p) * 32 + d] = f2bf(val);
        }
      }
    }
  }
}

// ---------------- window attention via MFMA: one wave per (window, head); N=49, dh=32 -------
// qb/kb/vb blocked (w,h,p,d) bf16: this block's q/k/v are 3 contiguous 3.1KB streams.
// S^T = mfma(K,Q): C-layout col=q=lane&15, row=m -> softmax over m = 16 in-lane vals +
// shfl_xor(16,32). P normalized in-reg, packed bf16, bounced through LDS Pl[q][mp]
// (stride 36 u32) to convert C-layout -> A-frag. PV = mfma(P,V). Padded rows/cols masked
// to -1e30 pre-softmax (invalid-q columns land only in unwritten out rows).
__global__ __launch_bounds__(64) void attn_kernel(
    const u16* __restrict__ qb, const u16* __restrict__ kb, const u16* __restrict__ vb,
    const float* __restrict__ btab, u16* __restrict__ out) {
  __shared__ float bcol[176];
  __shared__ u32 Pl[64 * 36];
  int blk = blockIdx.x;
  int h = blk & 15, w = blk >> 4;
  int lane = threadIdx.x;
  int c = lane & 15, g = lane >> 4;
  int hc = h * 32;
  size_t base = (size_t)blk * 1568;      // 49*32 elements per (w,h)

  for (int i = lane; i < 169; i += 64) bcol[i] = btab[i * 16 + h];

  const s16x8 z8 = (s16x8){0, 0, 0, 0, 0, 0, 0, 0};
  // Q as B-frags (col=q=lane&15, k=d=8g+j), K as A-frags (row=m=lane&15, k=d):
  // 16B/lane, 16 consecutive rows -> 1KB contiguous per frag load (fully coalesced)
  s16x8 qf[4], kf[4];
#pragma unroll
  for (int t = 0; t < 4; t++) {
    int qq = 16 * t + c;
    if (qq < 49) {
      qf[t] = *(const s16x8*)(qb + base + qq * 32 + g * 8);
      kf[t] = *(const s16x8*)(kb + base + qq * 32 + g * 8);
    } else { qf[t] = z8; kf[t] = z8; }
  }
  // V as B-frags for PV (col=d=16dt+c, k=m=32ks+8g+j): scalar bf16, 32B segments within
  // the contiguous 3.1KB v-block (L2-hot after first touch)
  s16x8 vf[2][2];
#pragma unroll
  for (int ks = 0; ks < 2; ks++)
#pragma unroll
    for (int dt = 0; dt < 2; dt++) {
      s16x8 v = z8;
#pragma unroll
      for (int j = 0; j < 8; j++) {
        int m = 32 * ks + 8 * g + j;
        if (m < 49) v[j] = (short)vb[base + m * 32 + 16 * dt + c];
      }
      vf[ks][dt] = v;
    }

  // S^T[m][q] tiles
  f32x4 s[4][4];
#pragma unroll
  for (int mt = 0; mt < 4; mt++)
#pragma unroll
    for (int nt = 0; nt < 4; nt++)
      s[mt][nt] = __builtin_amdgcn_mfma_f32_16x16x32_bf16(
          kf[mt], qf[nt], (f32x4){0.f, 0.f, 0.f, 0.f}, 0, 0, 0);

  // per-lane bias index tables: bidx = (qi*13+qj+84) - (mi*13+mj)
  int qb_[4]; bool qv[4];
#pragma unroll
  for (int nt = 0; nt < 4; nt++) {
    int qq = 16 * nt + c;
    qv[nt] = qq < 49;
    int qi = qq / 7, qj = qq - qi * 7;
    qb_[nt] = qi * 13 + qj + 84;
  }
  int mb_[4][4]; bool mv[4][4];
#pragma unroll
  for (int mt = 0; mt < 4; mt++)
#pragma unroll
    for (int r = 0; r < 4; r++) {
      int m = 16 * mt + 4 * g + r;
      mv[mt][r] = m < 49;
      int mi = m / 7, mj = m - mi * 7;
      mb_[mt][r] = mi * 13 + mj;
    }

  const float scale = 0.17677669529663689f;
#pragma unroll
  for (int nt = 0; nt < 4; nt++) {
    float mxl = -1e30f;
#pragma unroll
    for (int mt = 0; mt < 4; mt++)
#pragma unroll
      for (int r = 0; r < 4; r++) {
        int bi = qb_[nt] - mb_[mt][r];
        bi = bi < 0 ? 0 : (bi > 168 ? 168 : bi);          // clamp: no OOB LDS even when masked
        float v = (qv[nt] && mv[mt][r]) ? fmaf(s[mt][nt][r], scale, bcol[bi]) : -1e30f;
        s[mt][nt][r] = v;
        mxl = fmaxf(mxl, v);
      }
    mxl = fmaxf(mxl, __shfl_xor(mxl, 16));
    mxl = fmaxf(mxl, __shfl_xor(mxl, 32));
    float sml = 0.f;
#pragma unroll
    for (int mt = 0; mt < 4; mt++)
#pragma unroll
      for (int r = 0; r < 4; r++) {
        float ev = __expf(s[mt][nt][r] - mxl);
        s[mt][nt][r] = ev;
        sml += ev;
      }
    sml += __shfl_xor(sml, 16);
    sml += __shfl_xor(sml, 32);
    float inv = 1.f / sml;
#pragma unroll
    for (int mt = 0; mt < 4; mt++)
#pragma unroll
      for (int r = 0; r < 4; r++)
        s[mt][nt][r] *= inv;                              // fold softmax denom into P
  }

  // pack P to bf16 pairs -> LDS: Pl[q*36 + mp], u32 mp holds (m=2mp lo, m=2mp+1 hi)
#pragma unroll
  for (int nt = 0; nt < 4; nt++) {
    int qq = 16 * nt + c;
#pragma unroll
    for (int mt = 0; mt < 4; mt++) {
      u32 p0 = (u32)f2bf(s[mt][nt][0]) | ((u32)f2bf(s[mt][nt][1]) << 16);
      u32 p1 = (u32)f2bf(s[mt][nt][2]) | ((u32)f2bf(s[mt][nt][3]) << 16);
      int mp = 8 * mt + 2 * g;
      Pl[qq * 36 + mp] = p0;
      Pl[qq * 36 + mp + 1] = p1;
    }
  }
  asm volatile("" ::: "memory");   // keep ds_writes before ds_reads (single wave: DS in-order)

  f32x4 o[4][2];
#pragma unroll
  for (int qt = 0; qt < 4; qt++)
#pragma unroll
    for (int dt = 0; dt < 2; dt++) o[qt][dt] = (f32x4){0.f, 0.f, 0.f, 0.f};
#pragma unroll
  for (int qt = 0; qt < 4; qt++) {
#pragma unroll
    for (int ks = 0; ks < 2; ks++) {
      // A-frag: row=q=lane&15, k=m=32ks+8g+j -> 4 consecutive u32 at mp=16ks+4g
      s16x8 pf = *(const s16x8*)&Pl[(16 * qt + c) * 36 + 16 * ks + 4 * g];
#pragma unroll
      for (int dt = 0; dt < 2; dt++)
        o[qt][dt] = __builtin_amdgcn_mfma_f32_16x16x32_bf16(pf, vf[ks][dt], o[qt][dt], 0, 0, 0);
    }
  }
  // out C-layout: col=d=16dt+c, row=q=16qt+4g+r; 32B contiguous segments per (g,r)
#pragma unroll
  for (int qt = 0; qt < 4; qt++)
#pragma unroll
    for (int dt = 0; dt < 2; dt++)
#pragma unroll
      for (int r = 0; r < 4; r++) {
        int qq = 16 * qt + 4 * g + r;
        if (qq < 49)
          out[((size_t)w * 49 + qq) * 512 + hc + 16 * dt + c] = f2bf(o[qt][dt][r]);
      }
}

extern "C" void kernel_launch(void* const* d_in, const int* in_sizes, int n_in,
                              void* d_out, int out_size, void* d_ws, size_t ws_size,
                              hipStream_t stream) {
  (void)in_sizes; (void)n_in; (void)out_size; (void)ws_size;
  const float* x        = (const float*)d_in[0];
  const float* w_qkv    = (const float*)d_in[3];
  const float* b_qkv    = (const float*)d_in[4];
  const float* w_proj   = (const float*)d_in[5];
  const float* b_proj   = (const float*)d_in[6];
  const float* bias_tab = (const float*)d_in[7];
  const float* g1       = (const float*)d_in[8];
  const float* be1      = (const float*)d_in[9];
  const float* g2       = (const float*)d_in[10];
  const float* be2      = (const float*)d_in[11];
  const float* w1       = (const float*)d_in[12];
  const float* b1       = (const float*)d_in[13];
  const float* w2       = (const float*)d_in[14];
  const float* b2       = (const float*)d_in[15];

  char* ws = (char*)d_ws;
  // workspace layout (liveness-based reuse):
  u16* wqkvT  = (u16*)(ws + 0);            // 1536x512 bf16
  u16* wprojT = (u16*)(ws + 1572864);      //  512x512
  u16* w1T    = (u16*)(ws + 2097152);      // 2048x512
  u16* w2T    = (u16*)(ws + 4194304);      //  512x2048
  u16* xw     = (u16*)(ws + 6291456);      // R1: 50176x512 bf16 (windowed LN1 out)
  u16* attn_o = xw;                        // R1 reuse
  u16* h2     = xw;                        // R1 reuse
  char* R2    = ws + 57671680;
  u16* qb = (u16*)R2;                      // each 1024*16*49*32 bf16 = 51,380,224 B
  u16* kb = (u16*)(R2 + 51380224);
  u16* vb = (u16*)(R2 + 102760448);
  float* x_res = (float*)R2;               // R2 reuse (qkv dead after attention); w-order rows
  u16* hidden  = (u16*)(ws + 160432128);   // 50176x2048 bf16 (after x_res; vb dead by then)
  float* outp  = (float*)d_out;

  castT_kernel<<<dim3(1536 / 32, 512 / 32), 256, 0, stream>>>(w_qkv, wqkvT, 512, 1536);
  castT_kernel<<<dim3(512 / 32, 512 / 32), 256, 0, stream>>>(w_proj, wprojT, 512, 512);
  castT_kernel<<<dim3(2048 / 32, 512 / 32), 256, 0, stream>>>(w1, w1T, 512, 2048);
  castT_kernel<<<dim3(512 / 32, 2048 / 32), 256, 0, stream>>>(w2, w2T, 2048, 512);

  ln_kernel<1><<<12544, 256, 0, stream>>>(x, g1, be1, xw);
  gemm_bt<0><<<dim3(12, 392), 256, 0, stream>>>(xw, wqkvT, b_qkv, nullptr, nullptr, nullptr,
                                                1536, 512, qb, kb, vb);
  attn_kernel<<<16384, 64, 0, stream>>>(qb, kb, vb, bias_tab, attn_o);
  gemm_bt<1><<<dim3(4, 392), 256, 0, stream>>>(attn_o, wprojT, b_proj, x_res, nullptr, x,
                                               512, 512, nullptr, nullptr, nullptr);
  ln_kernel<0><<<12544, 256, 0, stream>>>(x_res, g2, be2, h2);
  gemm_bt<2><<<dim3(16, 392), 256, 0, stream>>>(h2, w1T, b1, nullptr, hidden, nullptr,
                                                2048, 512, nullptr, nullptr, nullptr);
  gemm_bt<3><<<dim3(4, 392), 256, 0, stream>>>(hidden, w2T, b2, outp, nullptr, x_res,
                                               512, 2048, nullptr, nullptr, nullptr);
}